// Round 8
// baseline (387.307 us; speedup 1.0000x reference)
//
#include <hip/hip_runtime.h>

typedef float f32x4 __attribute__((ext_vector_type(4)));
typedef _Float16 f16x8 __attribute__((ext_vector_type(8)));

#define NB 256
#define NL 256
#define NIN 256
#define ND 128
#define NH 64

// raw barrier: LDS-only drain (no vmcnt!) — global ops float across it
#define BAR_LDS() asm volatile("s_waitcnt lgkmcnt(0)\n\ts_barrier" ::: "memory")

// =====================================================================
// Kernel W: pack w_r|w_z|w_h + (k1-k2) into f16 MFMA-B fragment order.
// wpk[((nt*8+kc)*64+lane)*8+j]:
//   nt 0..23: B[col=(nt&7)*16+(lane&15)][k=kc*32+(lane>>4)*8+j] of gate nt>>3
//   nt 24   : col0 = k1-k2 (a-dot tile), other cols 0.   Total 200 KB.
// =====================================================================
__global__ void kwpack_kernel(const float* __restrict__ w_r,
                              const float* __restrict__ w_z,
                              const float* __restrict__ w_h,
                              const float* __restrict__ k1k2,
                              _Float16* __restrict__ wpk) {
  const int lane = threadIdx.x;        // 0..63
  const int nt = blockIdx.x;           // 0..24
  const int kc = blockIdx.y;           // 0..7
  const int l16 = lane & 15;
  const int k0 = kc * 32 + (lane >> 4) * 8;
  f16x8 f;
  if (nt < 24) {
    const float* wg = (nt < 8) ? w_r : (nt < 16) ? w_z : w_h;
    const int col = (nt & 7) * 16 + l16;
    const float4* p = (const float4*)(wg + (size_t)col * NIN + k0);
    float4 v0 = p[0], v1 = p[1];
    f[0] = (_Float16)v0.x; f[1] = (_Float16)v0.y;
    f[2] = (_Float16)v0.z; f[3] = (_Float16)v0.w;
    f[4] = (_Float16)v1.x; f[5] = (_Float16)v1.y;
    f[6] = (_Float16)v1.z; f[7] = (_Float16)v1.w;
  } else {
#pragma unroll
    for (int j = 0; j < 8; ++j)
      f[j] = (l16 == 0) ? (_Float16)(k1k2[k0 + j] - k1k2[NIN + k0 + j])
                        : (_Float16)0.f;
  }
  *(f16x8*)&wpk[(((size_t)nt * 8 + kc) * 64 + lane) * 8] = f;
}

// =====================================================================
// Kernel C v6 (fully fused): 256 blocks x 256 threads, one batch each.
// Per 16-step chunk boundary: mini-GEMM builds X (3 gates) + a inline
// from x (regs, loaded 3 steps early) and wpk (L2).  Steps: R4/R7-proven
// MFMA scan (1 lgkm-only barrier/step, pipelined ieff/hist state).
// Lessons kept: per-wave live VGPR < ~256 (R5 spill = 2x); out[] stores
// never vmcnt-drained; A-frags are raw ds_reads (MFMA linearity folds
// a/(1-a) into the epilogue).
// =====================================================================
__global__ __launch_bounds__(256, 1) void kscan_kernel(
    const float* __restrict__ u_r, const float* __restrict__ u_z,
    const float* __restrict__ u_h, const float* __restrict__ b_r,
    const float* __restrict__ b_z, const float* __restrict__ b_h,
    const int* __restrict__ cor, const float* __restrict__ x,
    const _Float16* __restrict__ wpk, float* __restrict__ out) {
  const int b = blockIdx.x;
  const int tid = threadIdx.x;
  const int lane = tid & 63;
  const int w = tid >> 6;        // wave id -> d range [32w, 32w+32)
  const int quad = lane >> 4;
  const int l16 = lane & 15;
  const int q8 = quad * 8;

  __shared__ __align__(16) _Float16 hist[(NL + 1) * NH];   // 32896 B
  __shared__ __align__(16) _Float16 Xl[3 * 16 * ND];       // 12288 B  [g][tin][d]
  __shared__ __align__(16) _Float16 x16[16 * 264];         // 8448 B (row pad +8)
  __shared__ __align__(16) float hprev32[2][ND];           // parity
  __shared__ __align__(16) _Float16 hprev16[2][NH];        // parity
  __shared__ float aCh[16];
  __shared__ int sCor[NL];

  // ---- persistent B fragments for the scan: u_g[n][k] f16 ----
  f16x8 bf[3][2][4];
#pragma unroll
  for (int g = 0; g < 3; ++g) {
    const float* ug = (g == 0) ? u_r : (g == 1) ? u_z : u_h;
#pragma unroll
    for (int tt = 0; tt < 2; ++tt) {
      const float* base = ug + (size_t)(32 * w + 16 * tt + l16) * ND;
#pragma unroll
      for (int kk = 0; kk < 4; ++kk) {
        const float4* p = (const float4*)(base + kk * 32 + q8);
        float4 v0 = p[0], v1 = p[1];
        f16x8 f;
        f[0] = (_Float16)v0.x; f[1] = (_Float16)v0.y;
        f[2] = (_Float16)v0.z; f[3] = (_Float16)v0.w;
        f[4] = (_Float16)v1.x; f[5] = (_Float16)v1.y;
        f[6] = (_Float16)v1.z; f[7] = (_Float16)v1.w;
        bf[g][tt][kk] = f;
      }
    }
  }

  const size_t rowb = (size_t)b * NL;
  if (tid < ND) { hprev32[0][tid] = 0.f; }
  if (tid < NH) { hprev16[0][tid] = (_Float16)0.f; hist[tid] = (_Float16)0.f; }
  sCor[tid] = cor[rowb + tid];

  // ---- x chunk-0 rows into registers (row = tid>>4, 64B per thread) ----
  float4 xg[4];
  {
    const float4* xr = (const float4*)(x + (rowb + (tid >> 4)) * NIN + (tid & 15) * 16);
#pragma unroll
    for (int i = 0; i < 4; ++i) xg[i] = xr[i];
  }

  const bool owner = (quad == 0);
  const int dd[2] = {32 * w + l16, 32 * w + l16 + 16};
  float bb[3][2] = {{0.f, 0.f}, {0.f, 0.f}, {0.f, 0.f}};
  if (owner) {
    bb[0][0] = b_r[dd[0]]; bb[0][1] = b_r[dd[1]];
    bb[1][0] = b_z[dd[0]]; bb[1][1] = b_z[dd[1]];
    bb[2][0] = b_h[dd[0]]; bb[2][1] = b_h[dd[1]];
  }
  __syncthreads();   // init visible

  // ---- pipelined per-step state (cor[b,0]==0 always -> ieff=0) ----
  float a_c = 0.f;
  int ieff_c = (sCor[0] == 0) ? 0 : sCor[0];
  bool pf_c = true;
  f16x8 af2 = *(const f16x8*)&hist[ieff_c * NH + q8];
  f16x8 af3 = *(const f16x8*)&hist[ieff_c * NH + 32 + q8];

  for (int t = 0; t < NL; ++t) {
    const int par = t & 1;
    const int tin = t & 15;

    // ================= chunk boundary: build X[t..t+15] =================
    if (tin == 0) {
      // cvt x regs -> padded f16 LDS (compiler waits the xg loads here)
      {
        f16x8 h0, h1;
        h0[0]=(_Float16)xg[0].x; h0[1]=(_Float16)xg[0].y; h0[2]=(_Float16)xg[0].z; h0[3]=(_Float16)xg[0].w;
        h0[4]=(_Float16)xg[1].x; h0[5]=(_Float16)xg[1].y; h0[6]=(_Float16)xg[1].z; h0[7]=(_Float16)xg[1].w;
        h1[0]=(_Float16)xg[2].x; h1[1]=(_Float16)xg[2].y; h1[2]=(_Float16)xg[2].z; h1[3]=(_Float16)xg[2].w;
        h1[4]=(_Float16)xg[3].x; h1[5]=(_Float16)xg[3].y; h1[6]=(_Float16)xg[3].z; h1[7]=(_Float16)xg[3].w;
        _Float16* dst = &x16[(tid >> 4) * 264 + (tid & 15) * 16];
        *(f16x8*)dst = h0;
        *(f16x8*)(dst + 8) = h1;
      }
      BAR_LDS();
      // mini-GEMM: wave w -> n-tiles 6w..6w+5; wave 0 also a-tile (nt 24)
      f32x4 gacc[6];
      f32x4 aacc = (f32x4){0.f, 0.f, 0.f, 0.f};
#pragma unroll
      for (int i = 0; i < 6; ++i) gacc[i] = (f32x4){0.f, 0.f, 0.f, 0.f};
      f16x8 gb[6], gbn[6], ab, abn;
#pragma unroll
      for (int i = 0; i < 6; ++i)
        gb[i] = *(const f16x8*)&wpk[(((size_t)(6 * w + i) * 8 + 0) * 64 + lane) * 8];
      if (w == 0) ab = *(const f16x8*)&wpk[(((size_t)24 * 8 + 0) * 64 + lane) * 8];
      for (int kc = 0; kc < 8; ++kc) {
        f16x8 af = *(const f16x8*)&x16[l16 * 264 + kc * 32 + q8];
        if (kc < 7) {
#pragma unroll
          for (int i = 0; i < 6; ++i)
            gbn[i] = *(const f16x8*)&wpk[(((size_t)(6 * w + i) * 8 + kc + 1) * 64 + lane) * 8];
          if (w == 0) abn = *(const f16x8*)&wpk[(((size_t)24 * 8 + kc + 1) * 64 + lane) * 8];
        }
#pragma unroll
        for (int i = 0; i < 6; ++i)
          gacc[i] = __builtin_amdgcn_mfma_f32_16x16x32_f16(af, gb[i], gacc[i], 0, 0, 0);
        if (w == 0) aacc = __builtin_amdgcn_mfma_f32_16x16x32_f16(af, ab, aacc, 0, 0, 0);
#pragma unroll
        for (int i = 0; i < 6; ++i) gb[i] = gbn[i];
        ab = abn;
      }
      // C writes: col=l16 (n), row=quad*4+r (m = tin within chunk)
#pragma unroll
      for (int i = 0; i < 6; ++i) {
        const int nt = 6 * w + i;
        const int g = nt >> 3;
        const int dc = (nt & 7) * 16 + l16;
#pragma unroll
        for (int r = 0; r < 4; ++r)
          Xl[g * 2048 + (quad * 4 + r) * 128 + dc] = (_Float16)gacc[i][r];
      }
      if (w == 0 && l16 == 0) {
#pragma unroll
        for (int r = 0; r < 4; ++r)
          aCh[quad * 4 + r] = 1.f / (1.f + __expf(-aacc[r]));
      }
      BAR_LDS();
      a_c = aCh[0];
    }

    const float a = a_c;
    const float oma = 1.f - a;
    const int ieff = ieff_c;

    // ---- issue x regs for the NEXT chunk, 3 steps ahead ----
    if (tin == 13 && t + 3 < NL) {
      const float4* xr = (const float4*)(x + (rowb + t + 3 + (tid >> 4)) * NIN + (tid & 15) * 16);
#pragma unroll
      for (int i = 0; i < 4; ++i) xg[i] = xr[i];
    }

    // ---- A frags: raw ds_reads; hist frag prefetched unless just written
    if (!pf_c) {
      af2 = *(const f16x8*)&hist[ieff * NH + q8];
      af3 = *(const f16x8*)&hist[ieff * NH + 32 + q8];
    }
    f16x8 af0 = *(const f16x8*)&hprev16[par][q8];
    f16x8 af1 = *(const f16x8*)&hprev16[par][32 + q8];

    // ---- X + md reads for this step (owner lanes; from LDS) ----
    float xv[3][2], md[2];
    if (owner) {
      const _Float16* xp = &Xl[tin * 128];
#pragma unroll
      for (int g = 0; g < 3; ++g) {
        xv[g][0] = (float)xp[g * 2048 + dd[0]];
        xv[g][1] = (float)xp[g * 2048 + dd[1]];
      }
      if (w < 2) {
        md[0] = a * hprev32[par][dd[0]];
        md[1] = a * hprev32[par][dd[1]];
      } else if (ieff == t) {
        md[0] = oma * hprev32[par][dd[0]];
        md[1] = oma * hprev32[par][dd[1]];
      } else {
        md[0] = oma * (float)hist[ieff * NH + (dd[0] - NH)];
        md[1] = oma * (float)hist[ieff * NH + (dd[1] - NH)];
      }
    }

    // ---- MFMA: lo (k<64) and hi (k>=64) accumulators ----
    f32x4 accL[3][2], accH[3][2];
#pragma unroll
    for (int g = 0; g < 3; ++g)
#pragma unroll
      for (int tt = 0; tt < 2; ++tt) {
        accL[g][tt] = (f32x4){0.f, 0.f, 0.f, 0.f};
        accH[g][tt] = (f32x4){0.f, 0.f, 0.f, 0.f};
      }
#pragma unroll
    for (int g = 0; g < 3; ++g)
#pragma unroll
      for (int tt = 0; tt < 2; ++tt) {
        accL[g][tt] = __builtin_amdgcn_mfma_f32_16x16x32_f16(af0, bf[g][tt][0], accL[g][tt], 0, 0, 0);
        accH[g][tt] = __builtin_amdgcn_mfma_f32_16x16x32_f16(af2, bf[g][tt][2], accH[g][tt], 0, 0, 0);
        accL[g][tt] = __builtin_amdgcn_mfma_f32_16x16x32_f16(af1, bf[g][tt][1], accL[g][tt], 0, 0, 0);
        accH[g][tt] = __builtin_amdgcn_mfma_f32_16x16x32_f16(af3, bf[g][tt][3], accH[g][tt], 0, 0, 0);
      }

    // ---- prefetch step-(t+1) state (overlaps MFMA/epilogue) ----
    const int tn = (t < NL - 1) ? t + 1 : t;
    float a_n = (tin < 15) ? aCh[tin + 1] : 0.f;   // boundary resets a_c
    int c_n = sCor[tn];
    int ieff_n = (c_n == 0) ? tn : c_n;
    bool pf_n = (ieff_n <= t);         // row stable during this step?
    f16x8 af2n, af3n;
    if (pf_n) {
      af2n = *(const f16x8*)&hist[ieff_n * NH + q8];
      af3n = *(const f16x8*)&hist[ieff_n * NH + 32 + q8];
    }

    // ---- epilogue (owner lanes; row 0 of C => quad 0, reg 0) ----
    if (owner) {
#pragma unroll
      for (int tt = 0; tt < 2; ++tt) {
        float dr = a * accL[0][tt][0] + oma * accH[0][tt][0];
        float dz = a * accL[1][tt][0] + oma * accH[1][tt][0];
        float dh = a * accL[2][tt][0] + oma * accH[2][tt][0];
        float rr = 1.f / (1.f + __expf(-(xv[0][tt] + bb[0][tt] + dr)));
        float zz = 1.f / (1.f + __expf(-(xv[1][tt] + bb[1][tt] + dz)));
        float e2 = __expf(2.f * (xv[2][tt] + bb[2][tt] + rr * dh));
        float hh = (e2 - 1.f) / (e2 + 1.f);
        float h = (1.f - zz) * md[tt] + zz * hh;
        int d = dd[tt];
        out[(rowb + t) * ND + d] = h;      // never vmcnt-drained
        hprev32[par ^ 1][d] = h;
        if (d < NH) hprev16[par ^ 1][d] = (_Float16)h;
        else        hist[(t + 1) * NH + (d - NH)] = (_Float16)h;
      }
    }

    BAR_LDS();   // LDS drain only

    if (tin != 15) a_c = a_n;
    ieff_c = ieff_n; pf_c = pf_n;
    if (pf_n) { af2 = af2n; af3 = af3n; }
  }
}

// =====================================================================
extern "C" void kernel_launch(void* const* d_in, const int* in_sizes, int n_in,
                              void* d_out, int out_size, void* d_ws, size_t ws_size,
                              hipStream_t stream) {
  (void)in_sizes; (void)n_in; (void)out_size; (void)ws_size;
  const float* x    = (const float*)d_in[0];
  const int*   cor  = (const int*)d_in[1];
  const float* w_r  = (const float*)d_in[2];
  const float* b_r  = (const float*)d_in[3];
  const float* u_r  = (const float*)d_in[4];
  const float* w_z  = (const float*)d_in[5];
  const float* b_z  = (const float*)d_in[6];
  const float* u_z  = (const float*)d_in[7];
  const float* w_h  = (const float*)d_in[8];
  const float* b_h  = (const float*)d_in[9];
  const float* u_h  = (const float*)d_in[10];
  const float* k1k2 = (const float*)d_in[11];

  _Float16* wpk = (_Float16*)d_ws;   // 25 tiles x 8 kc x 64 lanes x 8 f16 = 200 KB

  kwpack_kernel<<<dim3(25, 8), dim3(64), 0, stream>>>(w_r, w_z, w_h, k1k2, wpk);
  kscan_kernel<<<dim3(NB), dim3(256), 0, stream>>>(u_r, u_z, u_h, b_r, b_z, b_h,
                                                   cor, x, wpk, (float*)d_out);
}

// Round 9
// 371.072 us; speedup vs baseline: 1.0438x; 1.0438x over previous
//
#include <hip/hip_runtime.h>

typedef float f32x4 __attribute__((ext_vector_type(4)));
typedef _Float16 f16x8 __attribute__((ext_vector_type(8)));

#define NB 256
#define NL 256
#define NIN 256
#define ND 128
#define NH 64
#define BL (NB * NL)                 // 65536 rows
#define BLD ((size_t)BL * ND)        // 8,388,608 elements per gate
#define CH 16                        // X-staging chunk (steps)

// raw barrier: LDS-only drain (no vmcnt!) — global ops float across it
#define BAR_LDS() asm volatile("s_waitcnt lgkmcnt(0)\n\ts_barrier" ::: "memory")
#define WAIT_VM0() asm volatile("s_waitcnt vmcnt(0)" ::: "memory")

__device__ __forceinline__ void gload_lds16(const _Float16* gp, _Float16* lp) {
  __builtin_amdgcn_global_load_lds(
      (const __attribute__((address_space(1))) void*)gp,
      (__attribute__((address_space(3))) void*)lp, 16, 0, 0);
}

// =====================================================================
// Kernel W: pack w_r|w_z|w_h (f32 [128][256]) into f16 fragment order.
// wpk[((nt*8+kc)*64+lane)*8+j] = w_gate[(nt&7)*16+(lane&15)]
//                                 [kc*32+(lane>>4)*8+j];  192 KB, L2-hot.
// =====================================================================
__global__ void kwpack_kernel(const float* __restrict__ w_r,
                              const float* __restrict__ w_z,
                              const float* __restrict__ w_h,
                              _Float16* __restrict__ wpk) {
  const int lane = threadIdx.x;        // 0..63
  const int nt = blockIdx.x;           // 0..23
  const int kc = blockIdx.y;           // 0..7
  const float* wg = (nt < 8) ? w_r : (nt < 16) ? w_z : w_h;
  const int col = (nt & 7) * 16 + (lane & 15);
  const int k0 = kc * 32 + (lane >> 4) * 8;
  const float4* p = (const float4*)(wg + (size_t)col * NIN + k0);
  float4 v0 = p[0], v1 = p[1];
  f16x8 f;
  f[0] = (_Float16)v0.x; f[1] = (_Float16)v0.y;
  f[2] = (_Float16)v0.z; f[3] = (_Float16)v0.w;
  f[4] = (_Float16)v1.x; f[5] = (_Float16)v1.y;
  f[6] = (_Float16)v1.z; f[7] = (_Float16)v1.w;
  *(f16x8*)&wpk[(((size_t)nt * 8 + kc) * 64 + lane) * 8] = f;
}

// =====================================================================
// Kernel B v4 (fused, R7-proven ~35 us): per 64-row tile reads x ONCE,
// all 3 gate projections (B streamed from wpk/L2, no w staging) + the
// ka sigmoid inline. 1024 blocks x 256 threads.
// =====================================================================
__global__ __launch_bounds__(256, 2) void kproj_kernel(
    const float* __restrict__ x, const _Float16* __restrict__ wpk,
    const float* __restrict__ k1k2, _Float16* __restrict__ wsX,
    float* __restrict__ wsA) {
  const int r0 = blockIdx.x * 64;

  __shared__ __align__(16) _Float16 Ah[2][64 * 40];   // 10240 B
  __shared__ float k12[NIN];                          // 1024 B

  const int tid = threadIdx.x;
  const int lane = tid & 63;
  const int w = tid >> 6;
  const int l16 = lane & 15;
  const int q8 = (lane >> 4) * 8;

  k12[tid] = k1k2[tid] - k1k2[NIN + tid];

  const int srow = tid >> 2;          // 0..63
  const int seg = tid & 3;            // 8-float segment within 32-float kc
  const float4* xrow4 = (const float4*)(x + (size_t)(r0 + srow) * NIN + seg * 8);

  f32x4 acc[6][4];                    // [n-tile][m-tile]
#pragma unroll
  for (int i = 0; i < 6; ++i)
#pragma unroll
    for (int mt = 0; mt < 4; ++mt) acc[i][mt] = (f32x4){0.f, 0.f, 0.f, 0.f};

  // preload kc=0: x regs + B frags
  float4 xa = xrow4[0], xb = xrow4[1];
  f16x8 bcur[6], bnxt[6];
#pragma unroll
  for (int i = 0; i < 6; ++i)
    bcur[i] = *(const f16x8*)&wpk[(((size_t)(6 * w + i) * 8 + 0) * 64 + lane) * 8];

  float adot = 0.f;
  __syncthreads();                    // k12 visible

  for (int kc = 0; kc < 8; ++kc) {
    const int buf = kc & 1;
    // ---- ka partial (fp32, pre-truncation) ----
    {
      const float4* kk = (const float4*)&k12[kc * 32 + seg * 8];
      float4 k0 = kk[0], k1 = kk[1];
      adot += xa.x * k0.x + xa.y * k0.y + xa.z * k0.z + xa.w * k0.w +
              xb.x * k1.x + xb.y * k1.y + xb.z * k1.z + xb.w * k1.w;
    }
    // ---- cvt + stage x chunk ----
    {
      f16x8 h;
      h[0] = (_Float16)xa.x; h[1] = (_Float16)xa.y;
      h[2] = (_Float16)xa.z; h[3] = (_Float16)xa.w;
      h[4] = (_Float16)xb.x; h[5] = (_Float16)xb.y;
      h[6] = (_Float16)xb.z; h[7] = (_Float16)xb.w;
      *(f16x8*)&Ah[buf][srow * 40 + seg * 8] = h;
    }
    // ---- issue next-kc loads (x + B); in flight across the barrier ----
    if (kc < 7) {
      xa = xrow4[(kc + 1) * 8];
      xb = xrow4[(kc + 1) * 8 + 1];
#pragma unroll
      for (int i = 0; i < 6; ++i)
        bnxt[i] = *(const f16x8*)&wpk[(((size_t)(6 * w + i) * 8 + (kc + 1)) * 64 + lane) * 8];
    }
    BAR_LDS();   // lgkm drain only — global loads NOT drained

    // ---- A frags + MFMA ----
    f16x8 af[4];
#pragma unroll
    for (int mt = 0; mt < 4; ++mt)
      af[mt] = *(const f16x8*)&Ah[buf][(mt * 16 + l16) * 40 + q8];
#pragma unroll
    for (int i = 0; i < 6; ++i)
#pragma unroll
      for (int mt = 0; mt < 4; ++mt)
        acc[i][mt] = __builtin_amdgcn_mfma_f32_16x16x32_f16(af[mt], bcur[i], acc[i][mt], 0, 0, 0);
#pragma unroll
    for (int i = 0; i < 6; ++i) bcur[i] = bnxt[i];
  }

  // ---- ka reduce + store (lanes tid%4==0) ----
  adot += __shfl_xor(adot, 1);
  adot += __shfl_xor(adot, 2);
  if ((tid & 3) == 0) wsA[r0 + srow] = 1.f / (1.f + __expf(-adot));

  // ---- epilogue: C layout col=l16, row=(lane>>4)*4+r ----
#pragma unroll
  for (int i = 0; i < 6; ++i) {
    const int nt = 6 * w + i;
    const int g = nt >> 3;
    const int col = (nt & 7) * 16 + l16;
    _Float16* base = wsX + (size_t)g * BLD + col;
#pragma unroll
    for (int mt = 0; mt < 4; ++mt)
#pragma unroll
      for (int r = 0; r < 4; ++r) {
        int row = r0 + mt * 16 + (q8 >> 1) + r;   // (lane>>4)*4 + r
        base[(size_t)row * ND] = (_Float16)acc[i][mt][r];
      }
  }
}

// =====================================================================
// Kernel C (EXACT R6 body, proven 239.6 us): 4-wave MFMA scan, raw
// s_barrier (lgkm-only), pipelined (a,cor,ieff,hist-frag) state,
// async-chunked X from wsX. Codegen is fragile here — do not reorder.
// =====================================================================
__global__ __launch_bounds__(256, 1) void kscan_kernel(
    const float* __restrict__ u_r, const float* __restrict__ u_z,
    const float* __restrict__ u_h, const float* __restrict__ b_r,
    const float* __restrict__ b_z, const float* __restrict__ b_h,
    const int* __restrict__ cor, const _Float16* __restrict__ wsX,
    const float* __restrict__ wsA, float* __restrict__ out) {
  const int b = blockIdx.x;
  const int tid = threadIdx.x;
  const int lane = tid & 63;
  const int w = tid >> 6;        // wave id -> d range [32w, 32w+32)
  const int quad = lane >> 4;
  const int l16 = lane & 15;
  const int q8 = quad * 8;

  __shared__ __align__(16) _Float16 hist[(NL + 1) * NH];   // 32896 B
  __shared__ __align__(16) _Float16 Xl[2 * 3 * CH * ND];   // 24576 B
  __shared__ __align__(16) float hprev32[2][ND];           // 1024 B (parity)
  __shared__ __align__(16) _Float16 hprev16[2][NH];        // 256 B (parity)
  __shared__ float sA[NL];
  __shared__ int sCor[NL];

  // ---- B fragments: u_g[n][k] f16; n = 32w+16tt+l16, k = kk*32+q8+j ----
  f16x8 bf[3][2][4];
#pragma unroll
  for (int g = 0; g < 3; ++g) {
    const float* ug = (g == 0) ? u_r : (g == 1) ? u_z : u_h;
#pragma unroll
    for (int tt = 0; tt < 2; ++tt) {
      const float* base = ug + (size_t)(32 * w + 16 * tt + l16) * ND;
#pragma unroll
      for (int kk = 0; kk < 4; ++kk) {
        const float4* p = (const float4*)(base + kk * 32 + q8);
        float4 v0 = p[0], v1 = p[1];
        f16x8 f;
        f[0] = (_Float16)v0.x; f[1] = (_Float16)v0.y;
        f[2] = (_Float16)v0.z; f[3] = (_Float16)v0.w;
        f[4] = (_Float16)v1.x; f[5] = (_Float16)v1.y;
        f[6] = (_Float16)v1.z; f[7] = (_Float16)v1.w;
        bf[g][tt][kk] = f;
      }
    }
  }

  const size_t rowb = (size_t)b * NL;
  if (tid < ND) { hprev32[0][tid] = 0.f; }
  if (tid < NH) { hprev16[0][tid] = (_Float16)0.f; hist[tid] = (_Float16)0.f; }
  sA[tid] = wsA[rowb + tid];
  sCor[tid] = cor[rowb + tid];

  // ---- chunk 0 of X into Xl buf 0 (wave g loads gate g; 4x 1KB each) ----
  if (w < 3) {
    const _Float16* src = wsX + (size_t)w * BLD + rowb * ND + lane * 8;
    _Float16* dst = &Xl[w * (CH * ND)];
#pragma unroll
    for (int i = 0; i < 4; ++i)
      gload_lds16(src + i * 512, dst + i * 512);
  }

  const bool owner = (quad == 0);
  const int dd[2] = {32 * w + l16, 32 * w + l16 + 16};
  float bb[3][2] = {{0.f, 0.f}, {0.f, 0.f}, {0.f, 0.f}};
  if (owner) {
    bb[0][0] = b_r[dd[0]]; bb[0][1] = b_r[dd[1]];
    bb[1][0] = b_z[dd[0]]; bb[1][1] = b_z[dd[1]];
    bb[2][0] = b_h[dd[0]]; bb[2][1] = b_h[dd[1]];
  }
  __syncthreads();   // full drain once: chunk-0 loads + LDS init visible

  // ---- pipelined per-step state ----
  float a_c = sA[0];
  int c0 = sCor[0];
  int ieff_c = (c0 == 0) ? 0 : c0;
  bool pf_c = true;
  f16x8 af2 = *(const f16x8*)&hist[ieff_c * NH + q8];
  f16x8 af3 = *(const f16x8*)&hist[ieff_c * NH + 32 + q8];

  for (int t = 0; t < NL; ++t) {
    const int par = t & 1;
    const float a = a_c;
    const float oma = 1.f - a;
    const int ieff = ieff_c;
    const int cur = (t >> 4) & 1;
    const int tin = t & 15;

    // ---- issue next X chunk (once per 16 steps) ----
    if ((t & 15) == 0 && t + CH < NL && w < 3) {
      const _Float16* src = wsX + (size_t)w * BLD + (rowb + t + CH) * ND + lane * 8;
      _Float16* dst = &Xl[(cur ^ 1) * (3 * CH * ND) + w * (CH * ND)];
#pragma unroll
      for (int i = 0; i < 4; ++i)
        gload_lds16(src + i * 512, dst + i * 512);
    }

    // ---- hist frags: prefetched last step unless row was written last step
    if (!pf_c) {
      af2 = *(const f16x8*)&hist[ieff * NH + q8];
      af3 = *(const f16x8*)&hist[ieff * NH + 32 + q8];
    }
    f16x8 af0 = *(const f16x8*)&hprev16[par][q8];
    f16x8 af1 = *(const f16x8*)&hprev16[par][32 + q8];

    // ---- X + md reads for this step (owner lanes; from LDS) ----
    float xv[3][2], md[2];
    if (owner) {
      const _Float16* xp = &Xl[cur * (3 * CH * ND) + tin * ND];
#pragma unroll
      for (int g = 0; g < 3; ++g) {
        xv[g][0] = (float)xp[g * (CH * ND) + dd[0]];
        xv[g][1] = (float)xp[g * (CH * ND) + dd[1]];
      }
      if (w < 2) {
        md[0] = a * hprev32[par][dd[0]];
        md[1] = a * hprev32[par][dd[1]];
      } else if (ieff == t) {
        md[0] = oma * hprev32[par][dd[0]];
        md[1] = oma * hprev32[par][dd[1]];
      } else {
        md[0] = oma * (float)hist[ieff * NH + (dd[0] - NH)];
        md[1] = oma * (float)hist[ieff * NH + (dd[1] - NH)];
      }
    }

    // ---- MFMA: lo (k<64) and hi (k>=64) accumulators ----
    f32x4 accL[3][2], accH[3][2];
#pragma unroll
    for (int g = 0; g < 3; ++g)
#pragma unroll
      for (int tt = 0; tt < 2; ++tt) {
        accL[g][tt] = (f32x4){0.f, 0.f, 0.f, 0.f};
        accH[g][tt] = (f32x4){0.f, 0.f, 0.f, 0.f};
      }
#pragma unroll
    for (int g = 0; g < 3; ++g)
#pragma unroll
      for (int tt = 0; tt < 2; ++tt) {
        accL[g][tt] = __builtin_amdgcn_mfma_f32_16x16x32_f16(af0, bf[g][tt][0], accL[g][tt], 0, 0, 0);
        accH[g][tt] = __builtin_amdgcn_mfma_f32_16x16x32_f16(af2, bf[g][tt][2], accH[g][tt], 0, 0, 0);
        accL[g][tt] = __builtin_amdgcn_mfma_f32_16x16x32_f16(af1, bf[g][tt][1], accL[g][tt], 0, 0, 0);
        accH[g][tt] = __builtin_amdgcn_mfma_f32_16x16x32_f16(af3, bf[g][tt][3], accH[g][tt], 0, 0, 0);
      }

    // ---- prefetch step-(t+1) state (overlaps MFMA/epilogue) ----
    const int tn = (t < NL - 1) ? t + 1 : t;
    float a_n = sA[tn];
    int c_n = sCor[tn];
    int ieff_n = (c_n == 0) ? tn : c_n;
    bool pf_n = (ieff_n <= t);         // row stable during this step?
    f16x8 af2n, af3n;
    if (pf_n) {
      af2n = *(const f16x8*)&hist[ieff_n * NH + q8];
      af3n = *(const f16x8*)&hist[ieff_n * NH + 32 + q8];
    }

    // ---- epilogue (owner lanes; row 0 of C => quad 0, reg 0) ----
    if (owner) {
#pragma unroll
      for (int tt = 0; tt < 2; ++tt) {
        float dr = a * accL[0][tt][0] + oma * accH[0][tt][0];
        float dz = a * accL[1][tt][0] + oma * accH[1][tt][0];
        float dh = a * accL[2][tt][0] + oma * accH[2][tt][0];
        float rr = 1.f / (1.f + __expf(-(xv[0][tt] + bb[0][tt] + dr)));
        float zz = 1.f / (1.f + __expf(-(xv[1][tt] + bb[1][tt] + dz)));
        float e2 = __expf(2.f * (xv[2][tt] + bb[2][tt] + rr * dh));
        float hh = (e2 - 1.f) / (e2 + 1.f);
        float h = (1.f - zz) * md[tt] + zz * hh;
        int d = dd[tt];
        out[(rowb + t) * ND + d] = h;      // never drained per-step
        hprev32[par ^ 1][d] = h;
        if (d < NH) hprev16[par ^ 1][d] = (_Float16)h;
        else        hist[(t + 1) * NH + (d - NH)] = (_Float16)h;
      }
    }

    // ---- barrier: LDS drain only; vmcnt(0) only at chunk boundaries ----
    if ((t & 15) == 15) WAIT_VM0();
    BAR_LDS();

    a_c = a_n; ieff_c = ieff_n; pf_c = pf_n;
    if (pf_n) { af2 = af2n; af3 = af3n; }
  }
}

// =====================================================================
extern "C" void kernel_launch(void* const* d_in, const int* in_sizes, int n_in,
                              void* d_out, int out_size, void* d_ws, size_t ws_size,
                              hipStream_t stream) {
  (void)in_sizes; (void)n_in; (void)out_size; (void)ws_size;
  const float* x    = (const float*)d_in[0];
  const int*   cor  = (const int*)d_in[1];
  const float* w_r  = (const float*)d_in[2];
  const float* b_r  = (const float*)d_in[3];
  const float* u_r  = (const float*)d_in[4];
  const float* w_z  = (const float*)d_in[5];
  const float* b_z  = (const float*)d_in[6];
  const float* u_z  = (const float*)d_in[7];
  const float* w_h  = (const float*)d_in[8];
  const float* b_h  = (const float*)d_in[9];
  const float* u_h  = (const float*)d_in[10];
  const float* k1k2 = (const float*)d_in[11];

  _Float16* wsX = (_Float16*)d_ws;                                 // 48 MB
  float* wsA = (float*)((char*)d_ws + 3 * BLD * 2);                // 256 KB
  _Float16* wpk = (_Float16*)((char*)d_ws + 3 * BLD * 2 + BL * 4); // 192 KB

  kwpack_kernel<<<dim3(24, 8), dim3(64), 0, stream>>>(w_r, w_z, w_h, wpk);
  kproj_kernel<<<dim3(BL / 64), dim3(256), 0, stream>>>(x, wpk, k1k2, wsX, wsA);
  kscan_kernel<<<dim3(NB), dim3(256), 0, stream>>>(u_r, u_z, u_h, b_r, b_z, b_h,
                                                   cor, wsX, wsA, (float*)d_out);
}

// Round 10
// 354.923 us; speedup vs baseline: 1.0912x; 1.0455x over previous
//
#include <hip/hip_runtime.h>

typedef float f32x4 __attribute__((ext_vector_type(4)));
typedef _Float16 f16x8 __attribute__((ext_vector_type(8)));

#define NB 256
#define NL 256
#define NIN 256
#define ND 128
#define NH 64
#define BL (NB * NL)                 // 65536 rows
#define BLD ((size_t)BL * ND)        // 8,388,608 elements per gate
#define CH 16                        // X-staging chunk (steps)

// raw barrier: LDS-only drain (no vmcnt!) — global ops float across it
#define BAR_LDS() asm volatile("s_waitcnt lgkmcnt(0)\n\ts_barrier" ::: "memory")
#define WAIT_VM0() asm volatile("s_waitcnt vmcnt(0)" ::: "memory")

__device__ __forceinline__ void gload_lds16(const _Float16* gp, _Float16* lp) {
  __builtin_amdgcn_global_load_lds(
      (const __attribute__((address_space(1))) void*)gp,
      (__attribute__((address_space(3))) void*)lp, 16, 0, 0);
}

// =====================================================================
// Kernel W: pack w_r|w_z|w_h (f32 [128][256]) into f16 fragment order.
// wpk[((nt*8+kc)*64+lane)*8+j] = w_gate[(nt&7)*16+(lane&15)]
//                                 [kc*32+(lane>>4)*8+j];  192 KB, L2-hot.
// =====================================================================
__global__ void kwpack_kernel(const float* __restrict__ w_r,
                              const float* __restrict__ w_z,
                              const float* __restrict__ w_h,
                              _Float16* __restrict__ wpk) {
  const int lane = threadIdx.x;        // 0..63
  const int nt = blockIdx.x;           // 0..23
  const int kc = blockIdx.y;           // 0..7
  const float* wg = (nt < 8) ? w_r : (nt < 16) ? w_z : w_h;
  const int col = (nt & 7) * 16 + (lane & 15);
  const int k0 = kc * 32 + (lane >> 4) * 8;
  const float4* p = (const float4*)(wg + (size_t)col * NIN + k0);
  float4 v0 = p[0], v1 = p[1];
  f16x8 f;
  f[0] = (_Float16)v0.x; f[1] = (_Float16)v0.y;
  f[2] = (_Float16)v0.z; f[3] = (_Float16)v0.w;
  f[4] = (_Float16)v1.x; f[5] = (_Float16)v1.y;
  f[6] = (_Float16)v1.z; f[7] = (_Float16)v1.w;
  *(f16x8*)&wpk[(((size_t)nt * 8 + kc) * 64 + lane) * 8] = f;
}

// =====================================================================
// Kernel B v4 (fused, R7-proven ~35 us): per 64-row tile reads x ONCE,
// all 3 gate projections (B streamed from wpk/L2, no w staging) + the
// ka sigmoid inline. 1024 blocks x 256 threads.
// =====================================================================
__global__ __launch_bounds__(256, 2) void kproj_kernel(
    const float* __restrict__ x, const _Float16* __restrict__ wpk,
    const float* __restrict__ k1k2, _Float16* __restrict__ wsX,
    float* __restrict__ wsA) {
  const int r0 = blockIdx.x * 64;

  __shared__ __align__(16) _Float16 Ah[2][64 * 40];   // 10240 B
  __shared__ float k12[NIN];                          // 1024 B

  const int tid = threadIdx.x;
  const int lane = tid & 63;
  const int w = tid >> 6;
  const int l16 = lane & 15;
  const int q8 = (lane >> 4) * 8;

  k12[tid] = k1k2[tid] - k1k2[NIN + tid];

  const int srow = tid >> 2;          // 0..63
  const int seg = tid & 3;            // 8-float segment within 32-float kc
  const float4* xrow4 = (const float4*)(x + (size_t)(r0 + srow) * NIN + seg * 8);

  f32x4 acc[6][4];                    // [n-tile][m-tile]
#pragma unroll
  for (int i = 0; i < 6; ++i)
#pragma unroll
    for (int mt = 0; mt < 4; ++mt) acc[i][mt] = (f32x4){0.f, 0.f, 0.f, 0.f};

  // preload kc=0: x regs + B frags
  float4 xa = xrow4[0], xb = xrow4[1];
  f16x8 bcur[6], bnxt[6];
#pragma unroll
  for (int i = 0; i < 6; ++i)
    bcur[i] = *(const f16x8*)&wpk[(((size_t)(6 * w + i) * 8 + 0) * 64 + lane) * 8];

  float adot = 0.f;
  __syncthreads();                    // k12 visible

  for (int kc = 0; kc < 8; ++kc) {
    const int buf = kc & 1;
    // ---- ka partial (fp32, pre-truncation) ----
    {
      const float4* kk = (const float4*)&k12[kc * 32 + seg * 8];
      float4 k0 = kk[0], k1 = kk[1];
      adot += xa.x * k0.x + xa.y * k0.y + xa.z * k0.z + xa.w * k0.w +
              xb.x * k1.x + xb.y * k1.y + xb.z * k1.z + xb.w * k1.w;
    }
    // ---- cvt + stage x chunk ----
    {
      f16x8 h;
      h[0] = (_Float16)xa.x; h[1] = (_Float16)xa.y;
      h[2] = (_Float16)xa.z; h[3] = (_Float16)xa.w;
      h[4] = (_Float16)xb.x; h[5] = (_Float16)xb.y;
      h[6] = (_Float16)xb.z; h[7] = (_Float16)xb.w;
      *(f16x8*)&Ah[buf][srow * 40 + seg * 8] = h;
    }
    // ---- issue next-kc loads (x + B); in flight across the barrier ----
    if (kc < 7) {
      xa = xrow4[(kc + 1) * 8];
      xb = xrow4[(kc + 1) * 8 + 1];
#pragma unroll
      for (int i = 0; i < 6; ++i)
        bnxt[i] = *(const f16x8*)&wpk[(((size_t)(6 * w + i) * 8 + (kc + 1)) * 64 + lane) * 8];
    }
    BAR_LDS();   // lgkm drain only — global loads NOT drained

    // ---- A frags + MFMA ----
    f16x8 af[4];
#pragma unroll
    for (int mt = 0; mt < 4; ++mt)
      af[mt] = *(const f16x8*)&Ah[buf][(mt * 16 + l16) * 40 + q8];
#pragma unroll
    for (int i = 0; i < 6; ++i)
#pragma unroll
      for (int mt = 0; mt < 4; ++mt)
        acc[i][mt] = __builtin_amdgcn_mfma_f32_16x16x32_f16(af[mt], bcur[i], acc[i][mt], 0, 0, 0);
#pragma unroll
    for (int i = 0; i < 6; ++i) bcur[i] = bnxt[i];
  }

  // ---- ka reduce + store (lanes tid%4==0) ----
  adot += __shfl_xor(adot, 1);
  adot += __shfl_xor(adot, 2);
  if ((tid & 3) == 0) wsA[r0 + srow] = 1.f / (1.f + __expf(-adot));

  // ---- epilogue: C layout col=l16, row=(lane>>4)*4+r ----
#pragma unroll
  for (int i = 0; i < 6; ++i) {
    const int nt = 6 * w + i;
    const int g = nt >> 3;
    const int col = (nt & 7) * 16 + l16;
    _Float16* base = wsX + (size_t)g * BLD + col;
#pragma unroll
    for (int mt = 0; mt < 4; ++mt)
#pragma unroll
      for (int r = 0; r < 4; ++r) {
        int row = r0 + mt * 16 + (q8 >> 1) + r;   // (lane>>4)*4 + r
        base[(size_t)row * ND] = (_Float16)acc[i][mt][r];
      }
  }
}

// =====================================================================
// Kernel C v7: R6 body + two critical-path cuts:
//  (1) epilogue divides -> v_rcp_f32 (saves ~50 VALU instrs + ~100 cyc
//      of divide latency inside the serial sigmoid/tanh chain)
//  (2) accH (hist-half dots) pre-issued one step ahead when the hist row
//      is stable (pf), carried in registers -> epilogue waits only the
//      12 accL MFMAs (~192 cyc) instead of 24 (~384) on pf steps.
// Everything else byte-identical to the proven 239.6 us body.
// NOTE: per-wave live VGPR must stay < ~200 (R5 spill lesson).
// =====================================================================
__global__ __launch_bounds__(256, 1) void kscan_kernel(
    const float* __restrict__ u_r, const float* __restrict__ u_z,
    const float* __restrict__ u_h, const float* __restrict__ b_r,
    const float* __restrict__ b_z, const float* __restrict__ b_h,
    const int* __restrict__ cor, const _Float16* __restrict__ wsX,
    const float* __restrict__ wsA, float* __restrict__ out) {
  const int b = blockIdx.x;
  const int tid = threadIdx.x;
  const int lane = tid & 63;
  const int w = tid >> 6;        // wave id -> d range [32w, 32w+32)
  const int quad = lane >> 4;
  const int l16 = lane & 15;
  const int q8 = quad * 8;

  __shared__ __align__(16) _Float16 hist[(NL + 1) * NH];   // 32896 B
  __shared__ __align__(16) _Float16 Xl[2 * 3 * CH * ND];   // 24576 B
  __shared__ __align__(16) float hprev32[2][ND];           // 1024 B (parity)
  __shared__ __align__(16) _Float16 hprev16[2][NH];        // 256 B (parity)
  __shared__ float sA[NL];
  __shared__ int sCor[NL];

  // ---- B fragments: u_g[n][k] f16; n = 32w+16tt+l16, k = kk*32+q8+j ----
  f16x8 bf[3][2][4];
#pragma unroll
  for (int g = 0; g < 3; ++g) {
    const float* ug = (g == 0) ? u_r : (g == 1) ? u_z : u_h;
#pragma unroll
    for (int tt = 0; tt < 2; ++tt) {
      const float* base = ug + (size_t)(32 * w + 16 * tt + l16) * ND;
#pragma unroll
      for (int kk = 0; kk < 4; ++kk) {
        const float4* p = (const float4*)(base + kk * 32 + q8);
        float4 v0 = p[0], v1 = p[1];
        f16x8 f;
        f[0] = (_Float16)v0.x; f[1] = (_Float16)v0.y;
        f[2] = (_Float16)v0.z; f[3] = (_Float16)v0.w;
        f[4] = (_Float16)v1.x; f[5] = (_Float16)v1.y;
        f[6] = (_Float16)v1.z; f[7] = (_Float16)v1.w;
        bf[g][tt][kk] = f;
      }
    }
  }

  const size_t rowb = (size_t)b * NL;
  if (tid < ND) { hprev32[0][tid] = 0.f; }
  if (tid < NH) { hprev16[0][tid] = (_Float16)0.f; hist[tid] = (_Float16)0.f; }
  sA[tid] = wsA[rowb + tid];
  sCor[tid] = cor[rowb + tid];

  // ---- chunk 0 of X into Xl buf 0 (wave g loads gate g; 4x 1KB each) ----
  if (w < 3) {
    const _Float16* src = wsX + (size_t)w * BLD + rowb * ND + lane * 8;
    _Float16* dst = &Xl[w * (CH * ND)];
#pragma unroll
    for (int i = 0; i < 4; ++i)
      gload_lds16(src + i * 512, dst + i * 512);
  }

  const bool owner = (quad == 0);
  const int dd[2] = {32 * w + l16, 32 * w + l16 + 16};
  float bb[3][2] = {{0.f, 0.f}, {0.f, 0.f}, {0.f, 0.f}};
  if (owner) {
    bb[0][0] = b_r[dd[0]]; bb[0][1] = b_r[dd[1]];
    bb[1][0] = b_z[dd[0]]; bb[1][1] = b_z[dd[1]];
    bb[2][0] = b_h[dd[0]]; bb[2][1] = b_h[dd[1]];
  }
  __syncthreads();   // full drain once: chunk-0 loads + LDS init visible

  // ---- pipelined per-step state ----
  const f32x4 kZ = (f32x4){0.f, 0.f, 0.f, 0.f};
  float a_c = sA[0];
  int c0 = sCor[0];
  int ieff_c = (c0 == 0) ? 0 : c0;
  bool pf_c = true;
  // t=0: ieff=0 and hist row 0 is all-zero -> H-dots are exactly 0.
  f32x4 accH[3][2];
#pragma unroll
  for (int g = 0; g < 3; ++g)
#pragma unroll
    for (int tt = 0; tt < 2; ++tt) accH[g][tt] = kZ;

  for (int t = 0; t < NL; ++t) {
    const int par = t & 1;
    const float a = a_c;
    const float oma = 1.f - a;
    const int ieff = ieff_c;
    const int cur = (t >> 4) & 1;
    const int tin = t & 15;

    // ---- issue next X chunk (once per 16 steps) ----
    if ((t & 15) == 0 && t + CH < NL && w < 3) {
      const _Float16* src = wsX + (size_t)w * BLD + (rowb + t + CH) * ND + lane * 8;
      _Float16* dst = &Xl[(cur ^ 1) * (3 * CH * ND) + w * (CH * ND)];
#pragma unroll
      for (int i = 0; i < 4; ++i)
        gload_lds16(src + i * 512, dst + i * 512);
    }

    // ---- late-H path: hist row was written last step (ieff == t) ----
    if (!pf_c) {
      f16x8 a2 = *(const f16x8*)&hist[ieff * NH + q8];
      f16x8 a3 = *(const f16x8*)&hist[ieff * NH + 32 + q8];
#pragma unroll
      for (int g = 0; g < 3; ++g)
#pragma unroll
        for (int tt = 0; tt < 2; ++tt) {
          accH[g][tt] = __builtin_amdgcn_mfma_f32_16x16x32_f16(a2, bf[g][tt][2], kZ, 0, 0, 0);
          accH[g][tt] = __builtin_amdgcn_mfma_f32_16x16x32_f16(a3, bf[g][tt][3], accH[g][tt], 0, 0, 0);
        }
    }
    f16x8 af0 = *(const f16x8*)&hprev16[par][q8];
    f16x8 af1 = *(const f16x8*)&hprev16[par][32 + q8];

    // ---- X + md reads for this step (owner lanes; from LDS) ----
    float xv[3][2], md[2];
    if (owner) {
      const _Float16* xp = &Xl[cur * (3 * CH * ND) + tin * ND];
#pragma unroll
      for (int g = 0; g < 3; ++g) {
        xv[g][0] = (float)xp[g * (CH * ND) + dd[0]];
        xv[g][1] = (float)xp[g * (CH * ND) + dd[1]];
      }
      if (w < 2) {
        md[0] = a * hprev32[par][dd[0]];
        md[1] = a * hprev32[par][dd[1]];
      } else if (ieff == t) {
        md[0] = oma * hprev32[par][dd[0]];
        md[1] = oma * hprev32[par][dd[1]];
      } else {
        md[0] = oma * (float)hist[ieff * NH + (dd[0] - NH)];
        md[1] = oma * (float)hist[ieff * NH + (dd[1] - NH)];
      }
    }

    // ---- accL: lo-K (hprev16) dots — the only MFMAs the epilogue waits on
    f32x4 accL[3][2];
#pragma unroll
    for (int g = 0; g < 3; ++g)
#pragma unroll
      for (int tt = 0; tt < 2; ++tt) {
        accL[g][tt] = __builtin_amdgcn_mfma_f32_16x16x32_f16(af0, bf[g][tt][0], kZ, 0, 0, 0);
        accL[g][tt] = __builtin_amdgcn_mfma_f32_16x16x32_f16(af1, bf[g][tt][1], accL[g][tt], 0, 0, 0);
      }

    // ---- prefetch step-(t+1) state (overlaps MFMA/epilogue) ----
    const int tn = (t < NL - 1) ? t + 1 : t;
    float a_n = sA[tn];
    int c_n = sCor[tn];
    int ieff_n = (c_n == 0) ? tn : c_n;
    bool pf_n = (ieff_n <= t);         // row stable during this step?

    // ---- epilogue (owner lanes; row 0 of C => quad 0, reg 0) ----
    if (owner) {
#pragma unroll
      for (int tt = 0; tt < 2; ++tt) {
        float dr = a * accL[0][tt][0] + oma * accH[0][tt][0];
        float dz = a * accL[1][tt][0] + oma * accH[1][tt][0];
        float dh = a * accL[2][tt][0] + oma * accH[2][tt][0];
        float er = __expf(-(xv[0][tt] + bb[0][tt] + dr));
        float rr = __builtin_amdgcn_rcpf(1.f + er);
        float ez = __expf(-(xv[1][tt] + bb[1][tt] + dz));
        float zz = __builtin_amdgcn_rcpf(1.f + ez);
        float e2 = __expf(2.f * (xv[2][tt] + bb[2][tt] + rr * dh));
        float hh = (e2 - 1.f) * __builtin_amdgcn_rcpf(e2 + 1.f);
        float h = md[tt] + zz * (hh - md[tt]);   // (1-z)*m + z*hh
        int d = dd[tt];
        out[(rowb + t) * ND + d] = h;      // never drained per-step
        hprev32[par ^ 1][d] = h;
        if (d < NH) hprev16[par ^ 1][d] = (_Float16)h;
        else        hist[(t + 1) * NH + (d - NH)] = (_Float16)h;
      }
    }

    // ---- pre-issue next step's H dots if its hist row is already stable
    // (row ieff_n <= t was written in step ieff_n-1 <= t-1, i.e. before the
    // last barrier -> visible to all waves now). Issues in the epilogue's
    // shadow; off next step's critical path.
    if (pf_n) {
      f16x8 a2 = *(const f16x8*)&hist[ieff_n * NH + q8];
      f16x8 a3 = *(const f16x8*)&hist[ieff_n * NH + 32 + q8];
#pragma unroll
      for (int g = 0; g < 3; ++g)
#pragma unroll
        for (int tt = 0; tt < 2; ++tt) {
          accH[g][tt] = __builtin_amdgcn_mfma_f32_16x16x32_f16(a2, bf[g][tt][2], kZ, 0, 0, 0);
          accH[g][tt] = __builtin_amdgcn_mfma_f32_16x16x32_f16(a3, bf[g][tt][3], accH[g][tt], 0, 0, 0);
        }
    }

    // ---- barrier: LDS drain only; vmcnt(0) only at chunk boundaries ----
    if (tin == 15) WAIT_VM0();
    BAR_LDS();

    a_c = a_n; ieff_c = ieff_n; pf_c = pf_n;
  }
}

// =====================================================================
extern "C" void kernel_launch(void* const* d_in, const int* in_sizes, int n_in,
                              void* d_out, int out_size, void* d_ws, size_t ws_size,
                              hipStream_t stream) {
  (void)in_sizes; (void)n_in; (void)out_size; (void)ws_size;
  const float* x    = (const float*)d_in[0];
  const int*   cor  = (const int*)d_in[1];
  const float* w_r  = (const float*)d_in[2];
  const float* b_r  = (const float*)d_in[3];
  const float* u_r  = (const float*)d_in[4];
  const float* w_z  = (const float*)d_in[5];
  const float* b_z  = (const float*)d_in[6];
  const float* u_z  = (const float*)d_in[7];
  const float* w_h  = (const float*)d_in[8];
  const float* b_h  = (const float*)d_in[9];
  const float* u_h  = (const float*)d_in[10];
  const float* k1k2 = (const float*)d_in[11];

  _Float16* wsX = (_Float16*)d_ws;                                 // 48 MB
  float* wsA = (float*)((char*)d_ws + 3 * BLD * 2);                // 256 KB
  _Float16* wpk = (_Float16*)((char*)d_ws + 3 * BLD * 2 + BL * 4); // 192 KB

  kwpack_kernel<<<dim3(24, 8), dim3(64), 0, stream>>>(w_r, w_z, w_h, wpk);
  kproj_kernel<<<dim3(BL / 64), dim3(256), 0, stream>>>(x, wpk, k1k2, wsX, wsA);
  kscan_kernel<<<dim3(NB), dim3(256), 0, stream>>>(u_r, u_z, u_h, b_r, b_z, b_h,
                                                   cor, wsX, wsA, (float*)d_out);
}

// Round 11
// 341.815 us; speedup vs baseline: 1.1331x; 1.0383x over previous
//
#include <hip/hip_runtime.h>

typedef float f32x4 __attribute__((ext_vector_type(4)));
typedef _Float16 f16x8 __attribute__((ext_vector_type(8)));
typedef _Float16 f16x2 __attribute__((ext_vector_type(2)));

#define NB 256
#define NL 256
#define NIN 256
#define ND 128
#define NH 64
#define BL (NB * NL)                 // 65536 rows
#define BLD ((size_t)BL * ND)        // 8,388,608 elements per gate
#define CH 16                        // X-staging chunk (steps)

// raw barrier: LDS-only drain (no vmcnt!) — global ops float across it
#define BAR_LDS() asm volatile("s_waitcnt lgkmcnt(0)\n\ts_barrier" ::: "memory")
#define WAIT_VM0() asm volatile("s_waitcnt vmcnt(0)" ::: "memory")

__device__ __forceinline__ void gload_lds16(const _Float16* gp, _Float16* lp) {
  __builtin_amdgcn_global_load_lds(
      (const __attribute__((address_space(1))) void*)gp,
      (__attribute__((address_space(3))) void*)lp, 16, 0, 0);
}

// =====================================================================
// Kernel W: pack w_r|w_z|w_h (f32 [128][256]) into f16 fragment order.
// wpk[((nt*8+kc)*64+lane)*8+j] = w_gate[(nt&7)*16+(lane&15)]
//                                 [kc*32+(lane>>4)*8+j];  192 KB, L2-hot.
// =====================================================================
__global__ void kwpack_kernel(const float* __restrict__ w_r,
                              const float* __restrict__ w_z,
                              const float* __restrict__ w_h,
                              _Float16* __restrict__ wpk) {
  const int lane = threadIdx.x;        // 0..63
  const int nt = blockIdx.x;           // 0..23
  const int kc = blockIdx.y;           // 0..7
  const float* wg = (nt < 8) ? w_r : (nt < 16) ? w_z : w_h;
  const int col = (nt & 7) * 16 + (lane & 15);
  const int k0 = kc * 32 + (lane >> 4) * 8;
  const float4* p = (const float4*)(wg + (size_t)col * NIN + k0);
  float4 v0 = p[0], v1 = p[1];
  f16x8 f;
  f[0] = (_Float16)v0.x; f[1] = (_Float16)v0.y;
  f[2] = (_Float16)v0.z; f[3] = (_Float16)v0.w;
  f[4] = (_Float16)v1.x; f[5] = (_Float16)v1.y;
  f[6] = (_Float16)v1.z; f[7] = (_Float16)v1.w;
  *(f16x8*)&wpk[(((size_t)nt * 8 + kc) * 64 + lane) * 8] = f;
}

// =====================================================================
// Kernel B v5 (fused): as R7-proven, but the wsX column index is
// PERMUTED: pos(d=32w+16s+l16) = 32w + s + 2*l16, so the scan's owner
// lane reads its (d, d+16) pair as one b32.
// =====================================================================
__global__ __launch_bounds__(256, 2) void kproj_kernel(
    const float* __restrict__ x, const _Float16* __restrict__ wpk,
    const float* __restrict__ k1k2, _Float16* __restrict__ wsX,
    float* __restrict__ wsA) {
  const int r0 = blockIdx.x * 64;

  __shared__ __align__(16) _Float16 Ah[2][64 * 40];   // 10240 B
  __shared__ float k12[NIN];                          // 1024 B

  const int tid = threadIdx.x;
  const int lane = tid & 63;
  const int w = tid >> 6;
  const int l16 = lane & 15;
  const int q8 = (lane >> 4) * 8;

  k12[tid] = k1k2[tid] - k1k2[NIN + tid];

  const int srow = tid >> 2;          // 0..63
  const int seg = tid & 3;            // 8-float segment within 32-float kc
  const float4* xrow4 = (const float4*)(x + (size_t)(r0 + srow) * NIN + seg * 8);

  f32x4 acc[6][4];                    // [n-tile][m-tile]
#pragma unroll
  for (int i = 0; i < 6; ++i)
#pragma unroll
    for (int mt = 0; mt < 4; ++mt) acc[i][mt] = (f32x4){0.f, 0.f, 0.f, 0.f};

  // preload kc=0: x regs + B frags
  float4 xa = xrow4[0], xb = xrow4[1];
  f16x8 bcur[6], bnxt[6];
#pragma unroll
  for (int i = 0; i < 6; ++i)
    bcur[i] = *(const f16x8*)&wpk[(((size_t)(6 * w + i) * 8 + 0) * 64 + lane) * 8];

  float adot = 0.f;
  __syncthreads();                    // k12 visible

  for (int kc = 0; kc < 8; ++kc) {
    const int buf = kc & 1;
    // ---- ka partial (fp32, pre-truncation) ----
    {
      const float4* kk = (const float4*)&k12[kc * 32 + seg * 8];
      float4 k0 = kk[0], k1 = kk[1];
      adot += xa.x * k0.x + xa.y * k0.y + xa.z * k0.z + xa.w * k0.w +
              xb.x * k1.x + xb.y * k1.y + xb.z * k1.z + xb.w * k1.w;
    }
    // ---- cvt + stage x chunk ----
    {
      f16x8 h;
      h[0] = (_Float16)xa.x; h[1] = (_Float16)xa.y;
      h[2] = (_Float16)xa.z; h[3] = (_Float16)xa.w;
      h[4] = (_Float16)xb.x; h[5] = (_Float16)xb.y;
      h[6] = (_Float16)xb.z; h[7] = (_Float16)xb.w;
      *(f16x8*)&Ah[buf][srow * 40 + seg * 8] = h;
    }
    // ---- issue next-kc loads (x + B); in flight across the barrier ----
    if (kc < 7) {
      xa = xrow4[(kc + 1) * 8];
      xb = xrow4[(kc + 1) * 8 + 1];
#pragma unroll
      for (int i = 0; i < 6; ++i)
        bnxt[i] = *(const f16x8*)&wpk[(((size_t)(6 * w + i) * 8 + (kc + 1)) * 64 + lane) * 8];
    }
    BAR_LDS();   // lgkm drain only — global loads NOT drained

    // ---- A frags + MFMA ----
    f16x8 af[4];
#pragma unroll
    for (int mt = 0; mt < 4; ++mt)
      af[mt] = *(const f16x8*)&Ah[buf][(mt * 16 + l16) * 40 + q8];
#pragma unroll
    for (int i = 0; i < 6; ++i)
#pragma unroll
      for (int mt = 0; mt < 4; ++mt)
        acc[i][mt] = __builtin_amdgcn_mfma_f32_16x16x32_f16(af[mt], bcur[i], acc[i][mt], 0, 0, 0);
#pragma unroll
    for (int i = 0; i < 6; ++i) bcur[i] = bnxt[i];
  }

  // ---- ka reduce + store (lanes tid%4==0) ----
  adot += __shfl_xor(adot, 1);
  adot += __shfl_xor(adot, 2);
  if ((tid & 3) == 0) wsA[r0 + srow] = 1.f / (1.f + __expf(-adot));

  // ---- epilogue: permuted col pos = 32*(nt7>>1) + (nt7&1) + 2*l16 ----
#pragma unroll
  for (int i = 0; i < 6; ++i) {
    const int nt = 6 * w + i;
    const int g = nt >> 3;
    const int nt7 = nt & 7;
    const int colp = 32 * (nt7 >> 1) + (nt7 & 1) + 2 * l16;
    _Float16* base = wsX + (size_t)g * BLD + colp;
#pragma unroll
    for (int mt = 0; mt < 4; ++mt)
#pragma unroll
      for (int r = 0; r < 4; ++r) {
        int row = r0 + mt * 16 + (q8 >> 1) + r;   // (lane>>4)*4 + r
        base[(size_t)row * ND] = (_Float16)acc[i][mt][r];
      }
  }
}

// =====================================================================
// Kernel C v8: fused L/H MFMA via pre-scaled f16 A-frags.
//  - 6 accs / 12 MFMAs per step (was 12/24): acc = a*af_lo.U + oma*af_hi.U
//    folded by scaling frags with v_pk_mul_f16 (a known a step early).
//  - H-half pre-issued at end of step t (pf_n) into the carried accs;
//    late path (!pf_c) when hist row was written last step.
//  - hprev32 deleted: owner lanes carry their own h in registers for md.
//  - Xl cols permuted (see kproj): owner xv reads are single b32.
// NOTE: per-wave live VGPR must stay < ~200 (R5 spill lesson).
// =====================================================================
__global__ __launch_bounds__(256, 1) void kscan_kernel(
    const float* __restrict__ u_r, const float* __restrict__ u_z,
    const float* __restrict__ u_h, const float* __restrict__ b_r,
    const float* __restrict__ b_z, const float* __restrict__ b_h,
    const int* __restrict__ cor, const _Float16* __restrict__ wsX,
    const float* __restrict__ wsA, float* __restrict__ out) {
  const int b = blockIdx.x;
  const int tid = threadIdx.x;
  const int lane = tid & 63;
  const int w = tid >> 6;        // wave id -> d range [32w, 32w+32)
  const int quad = lane >> 4;
  const int l16 = lane & 15;
  const int q8 = quad * 8;

  __shared__ __align__(16) _Float16 hist[(NL + 1) * NH];   // 32896 B
  __shared__ __align__(16) _Float16 Xl[2 * 3 * CH * ND];   // 24576 B
  __shared__ __align__(16) _Float16 hprev16[2][NH];        // 256 B (parity)
  __shared__ float sA[NL];
  __shared__ int sCor[NL];

  // ---- B fragments: u_g[n][k] f16; n = 32w+16tt+l16, k = kk*32+q8+j ----
  f16x8 bf[3][2][4];
#pragma unroll
  for (int g = 0; g < 3; ++g) {
    const float* ug = (g == 0) ? u_r : (g == 1) ? u_z : u_h;
#pragma unroll
    for (int tt = 0; tt < 2; ++tt) {
      const float* base = ug + (size_t)(32 * w + 16 * tt + l16) * ND;
#pragma unroll
      for (int kk = 0; kk < 4; ++kk) {
        const float4* p = (const float4*)(base + kk * 32 + q8);
        float4 v0 = p[0], v1 = p[1];
        f16x8 f;
        f[0] = (_Float16)v0.x; f[1] = (_Float16)v0.y;
        f[2] = (_Float16)v0.z; f[3] = (_Float16)v0.w;
        f[4] = (_Float16)v1.x; f[5] = (_Float16)v1.y;
        f[6] = (_Float16)v1.z; f[7] = (_Float16)v1.w;
        bf[g][tt][kk] = f;
      }
    }
  }

  const size_t rowb = (size_t)b * NL;
  if (tid < NH) { hprev16[0][tid] = (_Float16)0.f; hist[tid] = (_Float16)0.f; }
  sA[tid] = wsA[rowb + tid];
  sCor[tid] = cor[rowb + tid];

  // ---- chunk 0 of X into Xl buf 0 (wave g loads gate g; 4x 1KB each) ----
  if (w < 3) {
    const _Float16* src = wsX + (size_t)w * BLD + rowb * ND + lane * 8;
    _Float16* dst = &Xl[w * (CH * ND)];
#pragma unroll
    for (int i = 0; i < 4; ++i)
      gload_lds16(src + i * 512, dst + i * 512);
  }

  const bool owner = (quad == 0);
  const int dd[2] = {32 * w + l16, 32 * w + l16 + 16};
  const int xpos = 32 * w + 2 * l16;   // permuted pair position
  float bb[3][2] = {{0.f, 0.f}, {0.f, 0.f}, {0.f, 0.f}};
  if (owner) {
    bb[0][0] = b_r[dd[0]]; bb[0][1] = b_r[dd[1]];
    bb[1][0] = b_z[dd[0]]; bb[1][1] = b_z[dd[1]];
    bb[2][0] = b_h[dd[0]]; bb[2][1] = b_h[dd[1]];
  }
  __syncthreads();   // full drain once: chunk-0 loads + LDS init visible

  // ---- pipelined per-step state ----
  const f32x4 kZ = (f32x4){0.f, 0.f, 0.f, 0.f};
  float a_c = sA[0];
  int c0 = sCor[0];
  int ieff_c = (c0 == 0) ? 0 : c0;
  bool pf_c = true;
  float hp[2] = {0.f, 0.f};            // own h_{t-1} (owner lanes)
  // t=0: hist row 0 all-zero -> H contribution 0: accs start at 0.
  f32x4 acc[3][2];
#pragma unroll
  for (int g = 0; g < 3; ++g)
#pragma unroll
    for (int tt = 0; tt < 2; ++tt) acc[g][tt] = kZ;

  for (int t = 0; t < NL; ++t) {
    const int par = t & 1;
    const float a = a_c;
    const float oma = 1.f - a;
    const int ieff = ieff_c;
    const int cur = (t >> 4) & 1;
    const int tin = t & 15;

    // ---- issue next X chunk (once per 16 steps) ----
    if (tin == 0 && t + CH < NL && w < 3) {
      const _Float16* src = wsX + (size_t)w * BLD + (rowb + t + CH) * ND + lane * 8;
      _Float16* dst = &Xl[(cur ^ 1) * (3 * CH * ND) + w * (CH * ND)];
#pragma unroll
      for (int i = 0; i < 4; ++i)
        gload_lds16(src + i * 512, dst + i * 512);
    }

    // ---- f16 splats of the gates' mixing weights ----
    const _Float16 ah16 = (_Float16)a;
    const _Float16 oh16 = (_Float16)oma;
    f16x8 asp, osp;
#pragma unroll
    for (int j = 0; j < 8; ++j) { asp[j] = ah16; osp[j] = oh16; }

    // ---- late-H path: hist row was written last step (ieff == t) ----
    if (!pf_c) {
      f16x8 g2 = *(const f16x8*)&hist[ieff * NH + q8];
      f16x8 g3 = *(const f16x8*)&hist[ieff * NH + 32 + q8];
      f16x8 s2 = g2 * osp, s3 = g3 * osp;
#pragma unroll
      for (int g = 0; g < 3; ++g)
#pragma unroll
        for (int tt = 0; tt < 2; ++tt) {
          acc[g][tt] = __builtin_amdgcn_mfma_f32_16x16x32_f16(s2, bf[g][tt][2], kZ, 0, 0, 0);
          acc[g][tt] = __builtin_amdgcn_mfma_f32_16x16x32_f16(s3, bf[g][tt][3], acc[g][tt], 0, 0, 0);
        }
    }

    // ---- lo-K A frags: read hprev16, scale by a (pk_mul) ----
    f16x8 h0 = *(const f16x8*)&hprev16[par][q8];
    f16x8 h1 = *(const f16x8*)&hprev16[par][32 + q8];
    f16x8 s0 = h0 * asp, s1 = h1 * asp;

    // ---- X + md for this step (owner lanes) ----
    float xv[3][2], md[2];
    if (owner) {
      const _Float16* xp = &Xl[cur * (3 * CH * ND) + tin * ND + xpos];
#pragma unroll
      for (int g = 0; g < 3; ++g) {
        f16x2 pr = *(const f16x2*)(xp + g * (CH * ND));
        xv[g][0] = (float)pr[0];
        xv[g][1] = (float)pr[1];
      }
      if (w < 2) {
        md[0] = a * hp[0]; md[1] = a * hp[1];
      } else if (ieff == t) {
        md[0] = oma * hp[0]; md[1] = oma * hp[1];
      } else {
        md[0] = oma * (float)hist[ieff * NH + (dd[0] - NH)];
        md[1] = oma * (float)hist[ieff * NH + (dd[1] - NH)];
      }
    }

    // ---- the 6 critical MFMAs: acc += (a*hprev_lo) . U_lo ----
#pragma unroll
    for (int g = 0; g < 3; ++g)
#pragma unroll
      for (int tt = 0; tt < 2; ++tt) {
        acc[g][tt] = __builtin_amdgcn_mfma_f32_16x16x32_f16(s0, bf[g][tt][0], acc[g][tt], 0, 0, 0);
        acc[g][tt] = __builtin_amdgcn_mfma_f32_16x16x32_f16(s1, bf[g][tt][1], acc[g][tt], 0, 0, 0);
      }

    // ---- prefetch step-(t+1) state ----
    const int tn = (t < NL - 1) ? t + 1 : t;
    float a_n = sA[tn];
    int c_n = sCor[tn];
    int ieff_n = (c_n == 0) ? tn : c_n;
    bool pf_n = (ieff_n <= t);         // row stable during this step?

    // ---- epilogue (owner lanes; row 0 of C => quad 0, reg 0) ----
    if (owner) {
#pragma unroll
      for (int tt = 0; tt < 2; ++tt) {
        float er = __expf(-(xv[0][tt] + bb[0][tt] + acc[0][tt][0]));
        float rr = __builtin_amdgcn_rcpf(1.f + er);
        float ez = __expf(-(xv[1][tt] + bb[1][tt] + acc[1][tt][0]));
        float zz = __builtin_amdgcn_rcpf(1.f + ez);
        float e2 = __expf(2.f * (xv[2][tt] + bb[2][tt] + rr * acc[2][tt][0]));
        float hh = (e2 - 1.f) * __builtin_amdgcn_rcpf(e2 + 1.f);
        float h = md[tt] + zz * (hh - md[tt]);   // (1-z)*m + z*hh
        hp[tt] = h;
        int d = dd[tt];
        out[(rowb + t) * ND + d] = h;      // never drained per-step
        if (d < NH) hprev16[par ^ 1][d] = (_Float16)h;
        else        hist[(t + 1) * NH + (d - NH)] = (_Float16)h;
      }
    }

    // ---- pre-issue next step's H half if its hist row is stable ----
    if (pf_n) {
      const _Float16 on16 = (_Float16)(1.f - a_n);
      f16x8 onsp;
#pragma unroll
      for (int j = 0; j < 8; ++j) onsp[j] = on16;
      f16x8 g2 = *(const f16x8*)&hist[ieff_n * NH + q8];
      f16x8 g3 = *(const f16x8*)&hist[ieff_n * NH + 32 + q8];
      f16x8 s2 = g2 * onsp, s3 = g3 * onsp;
#pragma unroll
      for (int g = 0; g < 3; ++g)
#pragma unroll
        for (int tt = 0; tt < 2; ++tt) {
          acc[g][tt] = __builtin_amdgcn_mfma_f32_16x16x32_f16(s2, bf[g][tt][2], kZ, 0, 0, 0);
          acc[g][tt] = __builtin_amdgcn_mfma_f32_16x16x32_f16(s3, bf[g][tt][3], acc[g][tt], 0, 0, 0);
        }
    }

    // ---- barrier: LDS drain only; vmcnt(0) only at chunk boundaries ----
    if (tin == 15) WAIT_VM0();
    BAR_LDS();

    a_c = a_n; ieff_c = ieff_n; pf_c = pf_n;
  }
}

// =====================================================================
extern "C" void kernel_launch(void* const* d_in, const int* in_sizes, int n_in,
                              void* d_out, int out_size, void* d_ws, size_t ws_size,
                              hipStream_t stream) {
  (void)in_sizes; (void)n_in; (void)out_size; (void)ws_size;
  const float* x    = (const float*)d_in[0];
  const int*   cor  = (const int*)d_in[1];
  const float* w_r  = (const float*)d_in[2];
  const float* b_r  = (const float*)d_in[3];
  const float* u_r  = (const float*)d_in[4];
  const float* w_z  = (const float*)d_in[5];
  const float* b_z  = (const float*)d_in[6];
  const float* u_z  = (const float*)d_in[7];
  const float* w_h  = (const float*)d_in[8];
  const float* b_h  = (const float*)d_in[9];
  const float* u_h  = (const float*)d_in[10];
  const float* k1k2 = (const float*)d_in[11];

  _Float16* wsX = (_Float16*)d_ws;                                 // 48 MB
  float* wsA = (float*)((char*)d_ws + 3 * BLD * 2);                // 256 KB
  _Float16* wpk = (_Float16*)((char*)d_ws + 3 * BLD * 2 + BL * 4); // 192 KB

  kwpack_kernel<<<dim3(24, 8), dim3(64), 0, stream>>>(w_r, w_z, w_h, wpk);
  kproj_kernel<<<dim3(BL / 64), dim3(256), 0, stream>>>(x, wpk, k1k2, wsX, wsA);
  kscan_kernel<<<dim3(NB), dim3(256), 0, stream>>>(u_r, u_z, u_h, b_r, b_z, b_h,
                                                   cor, wsX, wsA, (float*)d_out);
}